// Round 1
// baseline (303.652 us; speedup 1.0000x reference)
//
#include <hip/hip_runtime.h>

#define NB 32
#define TT 512
#define UU 100
#define UM 101   // U+1
#define VV 4096
#define NEG (-1e30f)

__device__ __forceinline__ float lae(float a, float b) {
    float m  = fmaxf(a, b);
    float nd = -fabsf(a - b);
    return m + __logf(1.0f + __expf(nd));
}

// Kernel A: emit[n][u][t] = enc[n,t,y[n,u]] + dec[n,u,y[n,u]]
// one block per (n,u); t-contiguous output so the DP kernel streams it.
__global__ void emit_gather_k(const float* __restrict__ enc,
                              const float* __restrict__ dec,
                              const int* __restrict__ tgt,
                              const int* __restrict__ ilen,
                              const int* __restrict__ tlen,
                              float* __restrict__ emit_ws) {
    int nu = blockIdx.x;
    int n = nu / UU, u = nu % UU;
    if (u >= tlen[n]) return;          // never an ancestor of the target cell
    int tin = ilen[n];
    int y = tgt[n * UU + u];
    float dval = dec[((size_t)n * UM + u) * VV + y];
    const float* ep = enc + (size_t)n * TT * VV + y;
    float* op = emit_ws + ((size_t)n * UU + u) * TT;
    for (int t = threadIdx.x; t < tin; t += blockDim.x)
        op[t] = ep[(size_t)t * VV] + dval;
}

// Kernel B: anti-diagonal wavefront DP, one 64-lane wave per batch element.
// lane L owns u = L (slot0) and u = L + 64 (slot1).
__global__ __launch_bounds__(64) void dp_k(const float* __restrict__ enc,
                                           const float* __restrict__ dec,
                                           const int* __restrict__ ilen,
                                           const int* __restrict__ tlen,
                                           const float* __restrict__ emit_ws,
                                           float* __restrict__ out) {
    int n = blockIdx.x;
    int lane = threadIdx.x;
    __shared__ float sbe[TT];
    const float* encn = enc + (size_t)n * TT * VV;
    for (int t = lane; t < TT; t += 64)
        sbe[t] = encn[(size_t)t * VV];          // enc[n][t][BLANK]

    int tin = ilen[n];
    int tg  = tlen[n];

    int u0 = lane, u1 = lane + 64;
    const float* decn = dec + (size_t)n * UM * VV;
    float bd0 = (u0 <= UU) ? decn[(size_t)u0 * VV] : 0.f;   // dec[n][u][BLANK]
    float bd1 = (u1 <= UU) ? decn[(size_t)u1 * VV] : 0.f;
    __syncthreads();

    const float* em0 = emit_ws + ((size_t)n * UU + (u0 >= 1 ? u0 - 1 : 0)) * TT;
    const float* em1 = emit_ws + ((size_t)n * UU + (u1 - 1)) * TT;

    float a0 = (lane == 0) ? 0.0f : NEG;   // alpha[0,0] = 0 at diagonal d=0
    float a1 = NEG;
    int dend = (tin - 1) + tg;
    float res0 = NEG, res1 = NEG;

    auto ld0 = [&](int d) -> float {
        int t = d - u0;
        bool ok = (u0 >= 1) && (u0 <= tg) && (t >= 0) && (t < tin);
        return ok ? em0[t] : 0.0f;
    };
    auto ld1 = [&](int d) -> float {
        int t = d - u1;
        bool ok = (u1 <= tg) && (t >= 0) && (t < tin);
        return ok ? em1[t] : 0.0f;
    };

    float e0 = ld0(1), e1 = ld1(1);
    for (int d = 1; d <= dend; ++d) {
        // distance-1 prefetch of next diagonal's emit values (off critical path)
        float ne0 = ld0(d + 1);
        float ne1 = ld1(d + 1);

        // neighbors from previous diagonal (old register values)
        float l0  = __shfl_up(a0, 1);
        float l1  = __shfl_up(a1, 1);
        float a63 = __shfl(a0, 63);
        if (lane == 0) l1 = a63;   // u=64's left neighbor is u=63 (slot0 of lane 63)

        {   // slot 0: cell (t, u0)
            int t = d - u0;
            if (t >= 0 && t < TT) {
                float bt = (t >= 1) ? (a0 + sbe[t - 1] + bd0) : NEG;
                float et = (u0 >= 1) ? (l0 + e0) : NEG;
                a0 = lae(bt, et);
                if (d == dend && u0 == tg) res0 = a0;
            }
        }
        {   // slot 1: cell (t, u1)
            int t = d - u1;
            if (t >= 0 && t < TT && u1 <= UU) {
                float bt = (t >= 1) ? (a1 + sbe[t - 1] + bd1) : NEG;
                float et = l1 + e1;             // u1 >= 64, emit path always exists
                a1 = lae(bt, et);
                if (d == dend && u1 == tg) res1 = a1;
            }
        }
        e0 = ne0; e1 = ne1;
    }

    float fin = sbe[tin - 1];
    if (u0 == tg) out[n] = res0 + fin + bd0;
    if (u1 == tg) out[n] = res1 + fin + bd1;
}

extern "C" void kernel_launch(void* const* d_in, const int* in_sizes, int n_in,
                              void* d_out, int out_size, void* d_ws, size_t ws_size,
                              hipStream_t stream) {
    const float* enc  = (const float*)d_in[0];
    const float* dec  = (const float*)d_in[1];
    const int*   tgt  = (const int*)d_in[2];
    const int*   ilen = (const int*)d_in[3];
    const int*   tlen = (const int*)d_in[4];
    float* out = (float*)d_out;
    float* emit_ws = (float*)d_ws;   // N*U*T floats = 6.55 MB

    hipLaunchKernelGGL(emit_gather_k, dim3(NB * UU), dim3(256), 0, stream,
                       enc, dec, tgt, ilen, tlen, emit_ws);
    hipLaunchKernelGGL(dp_k, dim3(NB), dim3(64), 0, stream,
                       enc, dec, ilen, tlen, emit_ws, out);
}